// Round 8
// baseline (335.631 us; speedup 1.0000x reference)
//
#include <hip/hip_runtime.h>
#include <math.h>

#define DD 1024
#define SS 4096
#define AP 128
#define LN_EPS 1e-6f
#define BK 32
#define BAND 384

typedef __bf16 bf16;
typedef __attribute__((ext_vector_type(4))) __bf16 bf16x4;
typedef __attribute__((ext_vector_type(8))) __bf16 bf16x8;
typedef __attribute__((ext_vector_type(4))) float f32x4;

#define GLOAD_LDS16(g, l)                                                   \
    __builtin_amdgcn_global_load_lds(                                        \
        (const __attribute__((address_space(1))) void*)(g),                  \
        (__attribute__((address_space(3))) void*)(l), 16, 0, 0)

// ---------------- merged prep: x cast | Wo cast | k1*g cast | 3 transposes | k1 row sums ----
__global__ __launch_bounds__(256) void prep_all(const float* __restrict__ x,
                                                const float* __restrict__ Wq,
                                                const float* __restrict__ Wk,
                                                const float* __restrict__ Wv,
                                                const float* __restrict__ Wo,
                                                const float* __restrict__ k1w,
                                                const float* __restrict__ k1b,
                                                const float* __restrict__ lng,
                                                const float* __restrict__ lnb,
                                                bf16* __restrict__ xb,
                                                bf16* __restrict__ Wob,
                                                bf16* __restrict__ k1g,
                                                bf16* __restrict__ Wtb,
                                                float* __restrict__ u1,
                                                float* __restrict__ c1b) {
    __shared__ float tile[64][65];
    const int bid = blockIdx.x;
    const int tid = threadIdx.x;
    if (bid < 16384) {  // x cast
        const int i = (bid * 256 + tid) * 4;
        const float4 a = *(const float4*)(x + i);
        bf16x4 o;
        o[0] = (__bf16)a.x; o[1] = (__bf16)a.y; o[2] = (__bf16)a.z; o[3] = (__bf16)a.w;
        *(bf16x4*)(xb + i) = o;
        return;
    }
    if (bid < 18432) {  // Wo cast / k1g = k1 * g cast
        const int b2 = bid - 16384;
        const int sel = b2 >> 10;
        const int bb = b2 & 1023;
        const float* s = sel ? k1w : Wo;
        bf16* d = sel ? k1g : Wob;
        const int i = (bb * 256 + tid) * 4;
        float4 a = *(const float4*)(s + i);
        if (sel) {
            const float4 g4 = *(const float4*)(lng + (i & (DD - 1)));
            a.x *= g4.x; a.y *= g4.y; a.z *= g4.z; a.w *= g4.w;
        }
        bf16x4 o;
        o[0] = (__bf16)a.x; o[1] = (__bf16)a.y; o[2] = (__bf16)a.z; o[3] = (__bf16)a.w;
        *(bf16x4*)(d + i) = o;
        return;
    }
    if (bid < 19200) {  // transpose-cast Wq/Wk/Wv
        const int t = bid - 18432;
        const int tz = t >> 8;
        const int tb_ = t & 255;
        const float* in = (tz == 0) ? Wq : (tz == 1) ? Wk : Wv;
        bf16* out = Wtb + ((size_t)tz << 20);
        const int r0 = (tb_ >> 4) * 64, c0 = (tb_ & 15) * 64;
        const int lr = tid >> 4;
        const int lc = (tid & 15) * 4;
#pragma unroll
        for (int rr = 0; rr < 4; rr++) {
            const int row = lr + rr * 16;
            const float4 v = *(const float4*)(in + (size_t)(r0 + row) * DD + c0 + lc);
            tile[row][lc] = v.x; tile[row][lc + 1] = v.y;
            tile[row][lc + 2] = v.z; tile[row][lc + 3] = v.w;
        }
        __syncthreads();
#pragma unroll
        for (int rr = 0; rr < 4; rr++) {
            const int row = lr + rr * 16;
            bf16x4 o;
            o[0] = (__bf16)tile[lc + 0][row];
            o[1] = (__bf16)tile[lc + 1][row];
            o[2] = (__bf16)tile[lc + 2][row];
            o[3] = (__bf16)tile[lc + 3][row];
            *(bf16x4*)(out + (size_t)(c0 + row) * DD + r0 + lc) = o;
        }
        return;
    }
    // prep_vec
    const int pv = bid - 19200;
    const int lane = tid & 63, wave = tid >> 6;
    const int n = pv * 4 + wave;
    const float* row = k1w + (size_t)n * DD + lane * 16;
    float su = 0.f, sb = 0.f;
#pragma unroll
    for (int q = 0; q < 4; q++) {
        const float4 a = *(const float4*)(row + q * 4);
        const float4 g4 = *(const float4*)(lng + lane * 16 + q * 4);
        const float4 b4 = *(const float4*)(lnb + lane * 16 + q * 4);
        su += a.x * g4.x + a.y * g4.y + a.z * g4.z + a.w * g4.w;
        sb += a.x * b4.x + a.y * b4.y + a.z * b4.z + a.w * b4.w;
    }
#pragma unroll
    for (int off = 32; off > 0; off >>= 1) {
        su += __shfl_xor(su, off);
        sb += __shfl_xor(sb, off);
    }
    if (lane == 0) {
        u1[n] = su;
        c1b[n] = sb + k1b[n];
    }
}

// ---------------- paired tiny 1024^3 GEMMs: z=0 -> Gt, z=1 -> W2 ----------------
__global__ __launch_bounds__(256) void gemm_pair(const bf16* __restrict__ A0,
                                                 const bf16* __restrict__ W0,
                                                 bf16* __restrict__ O0,
                                                 const bf16* __restrict__ A1,
                                                 const bf16* __restrict__ W1,
                                                 bf16* __restrict__ O1) {
    const bf16* A = blockIdx.z ? A1 : A0;
    const bf16* W = blockIdx.z ? W1 : W0;
    bf16* O = blockIdx.z ? O1 : O0;
    __shared__ bf16 As[128 * BK];
    __shared__ bf16 Bs[128 * BK];
    const int tid = threadIdx.x;
    const int lane = tid & 63;
    const int wave = tid >> 6;
    const int wm = wave & 1;
    const int wn = wave >> 1;
    const int m0 = blockIdx.y * 128;
    const int n0 = blockIdx.x * 128;

    const int c = wave * 64 + lane;
    const int ar = c >> 2;
    const int ac = (c & 3) << 3;
    char* AsB = (char*)As;
    char* BsB = (char*)Bs;
    const int lr = lane & 15;
    const int lk = (lane >> 4) << 3;

    f32x4 acc[4][4] = {};

    for (int kt = 0; kt < DD; kt += BK) {
        const bf16* ga0 = A + (size_t)(m0 + ar) * DD + kt + ac;
        const bf16* gb0 = W + (size_t)(n0 + ar) * DD + kt + ac;
        GLOAD_LDS16(ga0, AsB + wave * 1024);
        GLOAD_LDS16(ga0 + (size_t)64 * DD, AsB + 4096 + wave * 1024);
        GLOAD_LDS16(gb0, BsB + wave * 1024);
        GLOAD_LDS16(gb0 + (size_t)64 * DD, BsB + 4096 + wave * 1024);
        __syncthreads();

        bf16x8 af[4], bfr[4];
#pragma unroll
        for (int i = 0; i < 4; i++)
            af[i] = *(const bf16x8*)&As[(wm * 64 + i * 16 + lr) * BK + lk];
#pragma unroll
        for (int j = 0; j < 4; j++)
            bfr[j] = *(const bf16x8*)&Bs[(wn * 64 + j * 16 + lr) * BK + lk];
#pragma unroll
        for (int i = 0; i < 4; i++)
#pragma unroll
            for (int j = 0; j < 4; j++)
                acc[i][j] = __builtin_amdgcn_mfma_f32_16x16x32_bf16(af[i], bfr[j], acc[i][j], 0, 0, 0);
        __syncthreads();
    }

#pragma unroll
    for (int i = 0; i < 4; i++) {
        const int row = m0 + wm * 64 + i * 16 + ((lane >> 4) << 2);
#pragma unroll
        for (int j = 0; j < 4; j++) {
            const int col = n0 + wn * 64 + j * 16 + (lane & 15);
#pragma unroll
            for (int rr = 0; rr < 4; rr++)
                O[(size_t)(row + rr) * DD + col] = (__bf16)acc[i][j][rr];
        }
    }
}

// ================ 256x256 K-loop, measured-best structure (R0: 70.6us) ==================
// K=1024, BK=64, 512 thr, 8 waves (2M x 4N). LDS 128 KiB = 2 buffers x (A 2-khalf + B
// 2-khalf slices of [256][32]). 2 barriers + 2 counted vmcnt(8) per K-tile; 32-MFMA
// clusters; swizzle (verified 0 bank conflicts): phys 16B slot = logical ^ ((row>>1)&3),
// via pre-swizzled GLOBAL source + swizzled ds_read address.

#define KL_STAGE_A(tt, hh, bb)                                               \
    {                                                                        \
        const bf16* gp_ = Aop + gofsA + (tt) * 64 + (hh) * 32;               \
        GLOAD_LDS16(gp_, smem + (bb) + (hh) * 16384 + ldsW);                 \
        GLOAD_LDS16(gp_ + (size_t)128 * DD,                                  \
                    smem + (bb) + (hh) * 16384 + 8192 + ldsW);               \
    }
#define KL_STAGE_B(tt, hh, bb)                                               \
    {                                                                        \
        const bf16* gp_ = Bop + gofsB + (tt) * 64 + (hh) * 32;               \
        GLOAD_LDS16(gp_, smem + (bb) + 32768 + (hh) * 16384 + ldsW);         \
        GLOAD_LDS16(gp_ + (size_t)128 * DD,                                  \
                    smem + (bb) + 32768 + (hh) * 16384 + 8192 + ldsW);       \
    }
#define KL_READS_A(ks, mh)                                                   \
    af[0] = *(const bf16x8*)(sA + bufo + (ks) * 16384 + (mh) * 4096);        \
    af[1] = *(const bf16x8*)(sA + bufo + (ks) * 16384 + (mh) * 4096 + 1024); \
    af[2] = *(const bf16x8*)(sA + bufo + (ks) * 16384 + (mh) * 4096 + 2048); \
    af[3] = *(const bf16x8*)(sA + bufo + (ks) * 16384 + (mh) * 4096 + 3072);
#define KL_READS_B(ks)                                                       \
    bfr[0] = *(const bf16x8*)(sB + bufo + (ks) * 16384);                     \
    bfr[1] = *(const bf16x8*)(sB + bufo + (ks) * 16384 + 1024);              \
    bfr[2] = *(const bf16x8*)(sB + bufo + (ks) * 16384 + 2048);              \
    bfr[3] = *(const bf16x8*)(sB + bufo + (ks) * 16384 + 3072);
#define KL_MFMA4(I, MH)                                                      \
    acc[(MH) * 4 + I][0] = __builtin_amdgcn_mfma_f32_16x16x32_bf16(af[I], bfr[0], acc[(MH) * 4 + I][0], 0, 0, 0); \
    acc[(MH) * 4 + I][1] = __builtin_amdgcn_mfma_f32_16x16x32_bf16(af[I], bfr[1], acc[(MH) * 4 + I][1], 0, 0, 0); \
    acc[(MH) * 4 + I][2] = __builtin_amdgcn_mfma_f32_16x16x32_bf16(af[I], bfr[2], acc[(MH) * 4 + I][2], 0, 0, 0); \
    acc[(MH) * 4 + I][3] = __builtin_amdgcn_mfma_f32_16x16x32_bf16(af[I], bfr[3], acc[(MH) * 4 + I][3], 0, 0, 0);
#define KL_MFMA16(MH)                                                        \
    __builtin_amdgcn_s_setprio(1);                                           \
    KL_MFMA4(0, MH) KL_MFMA4(1, MH) KL_MFMA4(2, MH) KL_MFMA4(3, MH)          \
    __builtin_amdgcn_s_setprio(0);
#define KL_BARRIER(N) asm volatile("s_waitcnt vmcnt(" #N ")\n\ts_barrier" ::: "memory")

__device__ __forceinline__ void kloop256(const bf16* __restrict__ Aop,
                                         const bf16* __restrict__ Bop,
                                         const int m0, const int n0,
                                         char* smem, f32x4 (&acc)[8][4],
                                         const int tid, const int lane,
                                         const int wave, const int wm, const int wn) {
    // stage addressing: thread t -> slice row (t>>2)+q*128, 16B slot (t&3)^((t>>3)&3)
    const int grow = tid >> 2;
    const int gslot = (tid & 3) ^ ((tid >> 3) & 3);
    const size_t gofsA = (size_t)(m0 + grow) * DD + gslot * 8;
    const size_t gofsB = (size_t)(n0 + grow) * DD + gslot * 8;
    const int ldsW = wave * 1024;  // HW adds lane*16
    // read addressing: row = <base16> + (lane&15), slot = (lane>>4) ^ ((lane>>1)&3)
    const int sxo = (((lane >> 4) ^ ((lane >> 1) & 3)) << 4);
    const char* sA = smem + wm * 8192 + (lane & 15) * 64 + sxo;
    const char* sB = smem + 32768 + wn * 4096 + (lane & 15) * 64 + sxo;

    bf16x8 af[4], bfr[4];

    // prologue: 6 slices, 12 loads
    KL_STAGE_A(0, 0, 0) KL_STAGE_B(0, 0, 0)
    KL_STAGE_A(0, 1, 0) KL_STAGE_B(0, 1, 0)
    KL_STAGE_A(1, 0, 65536) KL_STAGE_B(1, 0, 65536)

    int bufo = 0;
    for (int t = 0; t < 15; t++) {
        const int nb = bufo ^ 65536;
        KL_BARRIER(8);                   // A[t][0],B[t][0] landed; 4 slices in flight
        KL_READS_A(0, 0) KL_READS_B(0)
        KL_STAGE_A(t + 1, 1, nb)
        KL_MFMA16(0)
        KL_READS_A(0, 1)
        KL_STAGE_B(t + 1, 1, nb)
        KL_MFMA16(1)
        KL_BARRIER(8);                   // A[t][1],B[t][1] landed
        KL_READS_A(1, 0) KL_READS_B(1)
        if (t < 14) { KL_STAGE_A(t + 2, 0, bufo) }
        KL_MFMA16(0)
        KL_READS_A(1, 1)
        if (t < 14) { KL_STAGE_B(t + 2, 0, bufo) }
        KL_MFMA16(1)
        bufo = nb;
    }
    // peeled t = 15 (bufo == 65536)
    KL_BARRIER(4);
    KL_READS_A(0, 0) KL_READS_B(0)
    KL_MFMA16(0)
    KL_READS_A(0, 1)
    KL_MFMA16(1)
    KL_BARRIER(0);
    KL_READS_A(1, 0) KL_READS_B(1)
    KL_MFMA16(0)
    KL_READS_A(1, 1)
    KL_MFMA16(1)
}

// ---------------- merged U / Vt2 GEMM: 256x256 tiles, 512 threads, grid 512 ----------
__global__ __launch_bounds__(512) void gemm_uv(const bf16* __restrict__ xb,
                                               const bf16* __restrict__ Gt,
                                               const bf16* __restrict__ W2,
                                               bf16* __restrict__ Ub,
                                               bf16* __restrict__ Vt2) {
    __shared__ char smem[131072];
    const int s = blockIdx.x;
    const int half = s >> 8;
    const int sh = s & 255;
    const int p = (sh & 7) | ((sh >> 5) << 3);  // xb panel 0..63; p % 8 == s % 8
    const int q = (sh >> 3) & 3;
    const bf16* A;
    const bf16* W;
    bf16* O;
    int m0, n0;
    size_t ldo;
    if (half == 0) {
        A = xb; W = Gt; O = Ub;
        m0 = p * 256; n0 = q * 256; ldo = DD;
    } else {
        A = W2; W = xb; O = Vt2;
        m0 = q * 256; n0 = p * 256; ldo = (size_t)4 * SS;
    }
    const int tid = threadIdx.x;
    const int lane = tid & 63;
    const int wave = tid >> 6;
    const int wm = wave & 1;
    const int wn = wave >> 1;

    f32x4 acc[8][4] = {};
    kloop256(A, W, m0, n0, smem, acc, tid, lane, wave, wm, wn);

#pragma unroll
    for (int a = 0; a < 8; a++) {
        const int row = m0 + wm * 128 + a * 16 + ((lane >> 4) << 2);
#pragma unroll
        for (int j = 0; j < 4; j++) {
            const int col = n0 + wn * 64 + j * 16 + (lane & 15);
#pragma unroll
            for (int rr = 0; rr < 4; rr++)
                O[(size_t)(row + rr) * ldo + col] = (__bf16)acc[a][j][rr];
        }
    }
}

// ---------------- k1 GEMM (256x256), folded LN1, partial-only output ------
__global__ __launch_bounds__(512) void gemm_k1(const bf16* __restrict__ T,
                                               const bf16* __restrict__ k1g,
                                               const float* __restrict__ part_t,
                                               const float* __restrict__ u1,
                                               const float* __restrict__ c1b,
                                               const float* __restrict__ lng,
                                               const float* __restrict__ k2w,
                                               float* __restrict__ part_h) {
    __shared__ char smem[131072];
    __shared__ float lmu[256], lrs[256];
    const int m0 = blockIdx.x * 256;
    const int n0 = blockIdx.y * 256;
    const int tid = threadIdx.x;
    const int lane = tid & 63;
    const int wave = tid >> 6;
    const int wm = wave & 1;
    const int wn = wave >> 1;

    // per-row LN1 stats from part_t (exact)
    if (tid < 256) {
        const float* p = part_t + (size_t)(m0 + tid) * 32;
        float s1 = 0.f, s2 = 0.f;
#pragma unroll
        for (int s = 0; s < 8; s++) {
            const float4 v = *(const float4*)(p + s * 4);
            s1 += v.x + v.z;
            s2 += v.y + v.w;
        }
        const float m = s1 * (1.f / DD);
        lmu[tid] = m;
        lrs[tid] = rsqrtf(s2 * (1.f / DD) - m * m + LN_EPS);
    }
    __syncthreads();  // publishes lmu/lrs; drains part_t loads so vmcnt counting starts at 0

    f32x4 acc[8][4] = {};
    kloop256(T, k1g, m0, n0, smem, acc, tid, lane, wave, wm, wn);

    float u1v[4], cbv[4], ugv[4];
#pragma unroll
    for (int j = 0; j < 4; j++) {
        const int col = n0 + wn * 64 + j * 16 + (lane & 15);
        u1v[j] = u1[col];
        cbv[j] = c1b[col];
        ugv[j] = lng[col] * k2w[col];
    }
    const int strip = blockIdx.y * 4 + wn;  // 16 strips of 64 cols
#pragma unroll
    for (int a = 0; a < 8; a++) {
#pragma unroll
        for (int rr = 0; rr < 4; rr++) {
            const int lrow = wm * 128 + a * 16 + ((lane >> 4) << 2) + rr;
            const int row = m0 + lrow;
            const float mr = lmu[lrow], rs = lrs[lrow];
            float s1 = 0.f, s2 = 0.f, s3 = 0.f;
#pragma unroll
            for (int j = 0; j < 4; j++) {
                const float v = rs * (acc[a][j][rr] - mr * u1v[j]) + cbv[j];
                const float h = fmaxf(v, 0.f);
                s1 += h; s2 += h * h; s3 += h * ugv[j];
            }
#pragma unroll
            for (int off = 8; off > 0; off >>= 1) {
                s1 += __shfl_xor(s1, off);
                s2 += __shfl_xor(s2, off);
                s3 += __shfl_xor(s3, off);
            }
            if ((lane & 15) == 0) {
                float* p = part_h + (size_t)row * 48 + strip * 3;
                p[0] = s1; p[1] = s2; p[2] = s3;
            }
        }
    }
}

// ---------------- FUSED attention A: S = U @ x_band^T -> masked softmax -> bf16 P -------
// 64-row tiles, 512 thr (8 waves 2M x 4N over 64x384), K=1024, BK=32 single-buffer.
// Eliminates the fp32 S tensor (50MB round-trip) and the separate softmax launch.
// Same LDS XOR swizzle as kloop256 (pre-swizzled global src + swizzled ds_read).
// t-mapping gives each XCD a contiguous 2048-row band chunk (~4.7MB ~= one L2).
__global__ __launch_bounds__(512) void attn_sp(const bf16* __restrict__ U,
                                               const bf16* __restrict__ X,
                                               bf16* __restrict__ P) {
    __shared__ bf16 As[64 * BK];    // 4KB  (reused as lredm/lreds after K-loop)
    __shared__ bf16 Bs[384 * BK];   // 24KB
    const int s = blockIdx.x;
    const int t = (s & 7) * 32 + ((s >> 3) >> 1) * 2 + ((s >> 3) & 1);  // bijective 0..255
    const int tid = threadIdx.x;
    const int lane = tid & 63;
    const int wave = tid >> 6;
    const int wm = wave & 1;       // 2 row-groups of 32
    const int wn = wave >> 1;      // 4 col-groups of 96
    const int m0 = t * 64;
    const long w0 = (long)(t >> 1) * 128 - 128;  // band start (global row); OOB -> guard buffers

    const int grow = tid >> 2;
    const int gslot = (tid & 3) ^ ((tid >> 3) & 3);
    const size_t gofsA = (size_t)(m0 + (grow & 63)) * DD + gslot * 8;  // used by waves<4 only
    const long gofsB = (w0 + grow) * (long)DD + gslot * 8;
    const int ldsW = wave * 1024;  // HW adds lane*16
    const int sxo = (((lane >> 4) ^ ((lane >> 1) & 3)) << 4);
    const char* sA = (const char*)As + (lane & 15) * 64 + sxo;
    const char* sB = (const char*)Bs + (lane & 15) * 64 + sxo;

    f32x4 acc[2][6] = {};

    for (int kt = 0; kt < DD; kt += BK) {
        if (wave < 4) { GLOAD_LDS16(U + gofsA + kt, (char*)As + ldsW); }
        GLOAD_LDS16(X + gofsB + kt, (char*)Bs + ldsW);
        GLOAD_LDS16(X + gofsB + (long)128 * DD + kt, (char*)Bs + 8192 + ldsW);
        GLOAD_LDS16(X + gofsB + (long)256 * DD + kt, (char*)Bs + 16384 + ldsW);
        __syncthreads();

        bf16x8 af[2], bfr[6];
#pragma unroll
        for (int i = 0; i < 2; i++)
            af[i] = *(const bf16x8*)(sA + wm * 2048 + i * 1024);
#pragma unroll
        for (int j = 0; j < 6; j++)
            bfr[j] = *(const bf16x8*)(sB + wn * 6144 + j * 1024);
#pragma unroll
        for (int i = 0; i < 2; i++)
#pragma unroll
            for (int j = 0; j < 6; j++)
                acc[i][j] = __builtin_amdgcn_mfma_f32_16x16x32_bf16(af[i], bfr[j], acc[i][j], 0, 0, 0);
        __syncthreads();
    }

    // ---- masked softmax over the 384-wide band, rows = m0 .. m0+63 ----
    float* lredm = (float*)As;        // [64 rows][4 wn]
    float* lreds = lredm + 256;       // [64 rows][4 wn]
    const int rbase = wm * 32 + ((lane >> 4) << 2);     // + i*16 + rr
    const int ib = (t << 6) & (SS - 1);                 // in-batch row base
    const int jst = ((t >> 1) & 31) * 128 - 128;        // in-batch band start
    const float scale = 0.03125f;

    float pmx[2][4];
#pragma unroll
    for (int i = 0; i < 2; i++)
#pragma unroll
        for (int rr = 0; rr < 4; rr++) {
            const int irow = ib + rbase + i * 16 + rr;
            float mx = -INFINITY;
#pragma unroll
            for (int j = 0; j < 6; j++) {
                const int jg = jst + wn * 96 + j * 16 + (lane & 15);
                const int dj = jg - irow;
                const bool valid = (jg >= 0) && (jg < SS) && (dj != 0) && (dj <= AP) && (dj >= -AP);
                const float sv = valid ? acc[i][j][rr] * scale : -INFINITY;
                acc[i][j][rr] = sv;
                mx = fmaxf(mx, sv);
            }
#pragma unroll
            for (int off = 8; off > 0; off >>= 1) mx = fmaxf(mx, __shfl_xor(mx, off));
            pmx[i][rr] = mx;
        }
    if ((lane & 15) == 0) {
#pragma unroll
        for (int i = 0; i < 2; i++)
#pragma unroll
            for (int rr = 0; rr < 4; rr++)
                lredm[(rbase + i * 16 + rr) * 4 + wn] = pmx[i][rr];
    }
    __syncthreads();

    float lsum[2][4], mv[2][4];
#pragma unroll
    for (int i = 0; i < 2; i++)
#pragma unroll
        for (int rr = 0; rr < 4; rr++) {
            const int ri = (rbase + i * 16 + rr) * 4;
            mv[i][rr] = fmaxf(fmaxf(lredm[ri], lredm[ri + 1]),
                              fmaxf(lredm[ri + 2], lredm[ri + 3]));
            float su = 0.f;
#pragma unroll
            for (int j = 0; j < 6; j++) {
                const float e = __expf(acc[i][j][rr] - mv[i][rr]);
                acc[i][j][rr] = e;
                su += e;
            }
#pragma unroll
            for (int off = 8; off > 0; off >>= 1) su += __shfl_xor(su, off);
            lsum[i][rr] = su;
        }
    if ((lane & 15) == 0) {
#pragma unroll
        for (int i = 0; i < 2; i++)
#pragma unroll
            for (int rr = 0; rr < 4; rr++)
                lreds[(rbase + i * 16 + rr) * 4 + wn] = lsum[i][rr];
    }
    __syncthreads();

#pragma unroll
    for (int i = 0; i < 2; i++)
#pragma unroll
        for (int rr = 0; rr < 4; rr++) {
            const int ri = (rbase + i * 16 + rr) * 4;
            const float inv = 1.f / (lreds[ri] + lreds[ri + 1] + lreds[ri + 2] + lreds[ri + 3]);
            const size_t ro = (size_t)(m0 + rbase + i * 16 + rr) * BAND;
#pragma unroll
            for (int j = 0; j < 6; j++)
                P[ro + wn * 96 + j * 16 + (lane & 15)] = (__bf16)(acc[i][j][rr] * inv);
        }
}

// ---------------- attention pass B + residual + T row-partials ----------------
// 128x256 tiles, 512 threads, grid (x = 128 t, y = 4 n-blocks of 256)
__global__ __launch_bounds__(512) void attn_pv_mfma(const bf16* __restrict__ P,
                                                    const bf16* __restrict__ Vt,
                                                    const bf16* __restrict__ xres,
                                                    bf16* __restrict__ T,
                                                    float* __restrict__ part_t) {
    __shared__ bf16 As[128 * BK];   // P tile   8KB
    __shared__ bf16 Bs[256 * BK];   // Vt tile 16KB
    const int tid = threadIdx.x;
    const int lane = tid & 63;
    const int wave = tid >> 6;     // 0..7
    const int wm = wave & 1;       // 2 m-strips of 64
    const int wn = wave >> 1;      // 4 n-strips of 64
    const int t = blockIdx.x;
    const int m0 = t * 128;
    const int n0 = blockIdx.y * 256;
    const bf16* Wb = Vt + (long)t * 128 - 128;

    const int ar = tid >> 2;           // 0..127
    const int ac = (tid & 3) << 3;
    char* AsB = (char*)As;
    char* BsB = (char*)Bs;
    const int lr = lane & 15;
    const int lk = (lane >> 4) << 3;

    f32x4 acc[4][4] = {};

    for (int kt = 0; kt < BAND; kt += BK) {
        const bf16* ga0 = P + (size_t)(m0 + ar) * BAND + kt + ac;
        const bf16* gb0 = Wb + (size_t)(n0 + ar) * (4 * SS) + kt + ac;
        GLOAD_LDS16(ga0, AsB + wave * 1024);
        GLOAD_LDS16(gb0, BsB + wave * 1024);
        GLOAD_LDS16(gb0 + (size_t)128 * (4 * SS), BsB + 8192 + wave * 1024);
        __syncthreads();

        bf16x8 af[4], bfr[4];
#pragma unroll
        for (int i = 0; i < 4; i++)
            af[i] = *(const bf16x8*)&As[(wm * 64 + i * 16 + lr) * BK + lk];
#pragma unroll
        for (int j = 0; j < 4; j++)
            bfr[j] = *(const bf16x8*)&Bs[(wn * 64 + j * 16 + lr) * BK + lk];
#pragma unroll
        for (int i = 0; i < 4; i++)
#pragma unroll
            for (int j = 0; j < 4; j++)
                acc[i][j] = __builtin_amdgcn_mfma_f32_16x16x32_bf16(af[i], bfr[j], acc[i][j], 0, 0, 0);
        __syncthreads();
    }

    const int strip = blockIdx.y * 4 + wn;  // 16 strips of 64 cols
#pragma unroll
    for (int i = 0; i < 4; i++) {
#pragma unroll
        for (int rr = 0; rr < 4; rr++) {
            const int row = m0 + wm * 64 + i * 16 + ((lane >> 4) << 2) + rr;
            float s1 = 0.f, s2 = 0.f;
#pragma unroll
            for (int j = 0; j < 4; j++) {
                const int col = n0 + wn * 64 + j * 16 + (lane & 15);
                const size_t idx = (size_t)row * DD + col;
                const __bf16 tv_b = (__bf16)(acc[i][j][rr] + (float)xres[idx]);
                T[idx] = tv_b;
                const float tv = (float)tv_b;
                s1 += tv; s2 += tv * tv;
            }
#pragma unroll
            for (int off = 8; off > 0; off >>= 1) {
                s1 += __shfl_xor(s1, off);
                s2 += __shfl_xor(s2, off);
            }
            if ((lane & 15) == 0) {
                float2 st; st.x = s1; st.y = s2;
                *(float2*)(part_t + (size_t)row * 32 + strip * 2) = st;
            }
        }
    }
}

// ---------------- reduce H partials -> sigmoid head ----------------
__global__ __launch_bounds__(256) void ln_k2_p(const float* __restrict__ part_h,
                                               const float* __restrict__ g,
                                               const float* __restrict__ bta,
                                               const float* __restrict__ w2,
                                               const float* __restrict__ b2,
                                               float* __restrict__ out) {
    __shared__ float red[256], red2[256];
    const int tid = threadIdx.x;
    const float4 g4 = *(const float4*)(g + tid * 4);
    const float4 w4 = *(const float4*)(w2 + tid * 4);
    const float4 b4 = *(const float4*)(bta + tid * 4);
    red[tid] = g4.x * w4.x + g4.y * w4.y + g4.z * w4.z + g4.w * w4.w;
    red2[tid] = b4.x * w4.x + b4.y * w4.y + b4.z * w4.z + b4.w * w4.w;
    __syncthreads();
    for (int s = 128; s > 0; s >>= 1) {
        if (tid < s) { red[tid] += red[tid + s]; red2[tid] += red2[tid + s]; }
        __syncthreads();
    }
    const float sum_u = red[0];
    const float sum_bw = red2[0];

    const int r = blockIdx.x * 256 + tid;
    const float* p = part_h + (size_t)r * 48;
    float s1 = 0.f, s2 = 0.f, s3 = 0.f;
#pragma unroll
    for (int s = 0; s < 16; s++) {
        s1 += p[s * 3 + 0];
        s2 += p[s * 3 + 1];
        s3 += p[s * 3 + 2];
    }
    const float m = s1 * (1.f / DD);
    const float var = s2 * (1.f / DD) - m * m;
    const float rs = rsqrtf(var + LN_EPS);
    const float z = rs * (s3 - m * sum_u) + sum_bw + b2[0];
    out[r] = 1.f / (1.f + __expf(-z));
}

extern "C" void kernel_launch(void* const* d_in, const int* in_sizes, int n_in,
                              void* d_out, int out_size, void* d_ws, size_t ws_size,
                              hipStream_t stream) {
    const float* x   = (const float*)d_in[0];
    const float* Wq  = (const float*)d_in[1];
    const float* Wk  = (const float*)d_in[2];
    const float* Wv  = (const float*)d_in[3];
    const float* Wo  = (const float*)d_in[4];
    const float* k1w = (const float*)d_in[5];
    const float* k1b = (const float*)d_in[6];
    const float* k2w = (const float*)d_in[7];
    const float* k2b = (const float*)d_in[8];
    const float* lng = (const float*)d_in[9];
    const float* lnb = (const float*)d_in[10];
    float* out = (float*)d_out;

    const int N = 4 * SS;  // 16384 rows
    char* ws = (char*)d_ws;
    // layout (MB). Banded passes read +/-512KB around xb and +/-256KB around Vt2 ->
    // neighbors must be valid bf16 (Ub | xb | Vt2 | P). Masked / zero-weighted.
    bf16*  Ub   = (bf16*)(ws);                          //   0..32
    bf16*  xb   = (bf16*)(ws + ((size_t)32  << 20));    //  32..64
    bf16*  Vt2  = (bf16*)(ws + ((size_t)64  << 20));    //  64..96  [1024][16384]
    bf16*  P    = (bf16*)(ws + ((size_t)96  << 20));    //  96..108
    bf16*  T    = (bf16*)(ws + ((size_t)164 << 20));    // 164..196
    bf16*  Wtb  = (bf16*)(ws + ((size_t)196 << 20));    // 196..202: Wq^T, Wk^T, Wv^T
    bf16*  Wqtb = Wtb;
    bf16*  Wktb = Wqtb + (1 << 20);
    bf16*  Wvtb = Wktb + (1 << 20);
    bf16*  Wob  = Wvtb + (1 << 20);                     // 202..204
    bf16*  k1g  = Wob  + (1 << 20);                     // 204..206
    bf16*  Gtb  = k1g  + (1 << 20);                     // 206..208
    bf16*  W2b  = Gtb  + (1 << 20);                     // 208..210
    float* u1     = (float*)(ws + ((size_t)210 << 20)); // 4 KB
    float* c1b    = u1 + DD;                            // 4 KB
    float* part_t = (float*)(ws + ((size_t)211 << 20)); // 211..213: [16384][16][2]
    float* part_h = (float*)(ws + ((size_t)214 << 20)); // 214..217: [16384][16][3]

    dim3 tb(256);

    prep_all<<<19456, tb, 0, stream>>>(x, Wq, Wk, Wv, Wo, k1w, k1b, lng, lnb,
                                       xb, Wob, k1g, Wtb, u1, c1b);

    // Gt = Wk^T @ Wq (bt-layout)  |  W2 = Wo @ Wv (bt on Wv^T)
    gemm_pair<<<dim3(8, 8, 2), tb, 0, stream>>>(Wktb, Wqtb, Gtb, Wob, Wvtb, W2b);

    gemm_uv<<<512, dim3(512), 0, stream>>>(xb, Gtb, W2b, Ub, Vt2);

    attn_sp<<<256, dim3(512), 0, stream>>>(Ub, xb, P);
    attn_pv_mfma<<<dim3(N / 128, 4), dim3(512), 0, stream>>>(P, Vt2, xb, T, part_t);

    gemm_k1<<<dim3(64, 4), dim3(512), 0, stream>>>(T, k1g, part_t, u1, c1b, lng, k2w, part_h);
    ln_k2_p<<<N / 256, tb, 0, stream>>>(part_h, lng, lnb, k2w, k2b, out);
}

// Round 9
// 316.735 us; speedup vs baseline: 1.0597x; 1.0597x over previous
//
#include <hip/hip_runtime.h>
#include <math.h>

#define DD 1024
#define SS 4096
#define AP 128
#define LN_EPS 1e-6f
#define BK 32
#define BAND 384

typedef __bf16 bf16;
typedef __attribute__((ext_vector_type(4))) __bf16 bf16x4;
typedef __attribute__((ext_vector_type(8))) __bf16 bf16x8;
typedef __attribute__((ext_vector_type(4))) float f32x4;

#define GLOAD_LDS16(g, l)                                                   \
    __builtin_amdgcn_global_load_lds(                                        \
        (const __attribute__((address_space(1))) void*)(g),                  \
        (__attribute__((address_space(3))) void*)(l), 16, 0, 0)

// ---------------- merged prep: x cast | Wo cast | k1*g cast | 3 transposes | k1 row sums ----
__global__ __launch_bounds__(256) void prep_all(const float* __restrict__ x,
                                                const float* __restrict__ Wq,
                                                const float* __restrict__ Wk,
                                                const float* __restrict__ Wv,
                                                const float* __restrict__ Wo,
                                                const float* __restrict__ k1w,
                                                const float* __restrict__ k1b,
                                                const float* __restrict__ lng,
                                                const float* __restrict__ lnb,
                                                bf16* __restrict__ xb,
                                                bf16* __restrict__ Wob,
                                                bf16* __restrict__ k1g,
                                                bf16* __restrict__ Wtb,
                                                float* __restrict__ u1,
                                                float* __restrict__ c1b) {
    __shared__ float tile[64][65];
    const int bid = blockIdx.x;
    const int tid = threadIdx.x;
    if (bid < 16384) {  // x cast
        const int i = (bid * 256 + tid) * 4;
        const float4 a = *(const float4*)(x + i);
        bf16x4 o;
        o[0] = (__bf16)a.x; o[1] = (__bf16)a.y; o[2] = (__bf16)a.z; o[3] = (__bf16)a.w;
        *(bf16x4*)(xb + i) = o;
        return;
    }
    if (bid < 18432) {  // Wo cast / k1g = k1 * g cast
        const int b2 = bid - 16384;
        const int sel = b2 >> 10;
        const int bb = b2 & 1023;
        const float* s = sel ? k1w : Wo;
        bf16* d = sel ? k1g : Wob;
        const int i = (bb * 256 + tid) * 4;
        float4 a = *(const float4*)(s + i);
        if (sel) {
            const float4 g4 = *(const float4*)(lng + (i & (DD - 1)));
            a.x *= g4.x; a.y *= g4.y; a.z *= g4.z; a.w *= g4.w;
        }
        bf16x4 o;
        o[0] = (__bf16)a.x; o[1] = (__bf16)a.y; o[2] = (__bf16)a.z; o[3] = (__bf16)a.w;
        *(bf16x4*)(d + i) = o;
        return;
    }
    if (bid < 19200) {  // transpose-cast Wq/Wk/Wv
        const int t = bid - 18432;
        const int tz = t >> 8;
        const int tb_ = t & 255;
        const float* in = (tz == 0) ? Wq : (tz == 1) ? Wk : Wv;
        bf16* out = Wtb + ((size_t)tz << 20);
        const int r0 = (tb_ >> 4) * 64, c0 = (tb_ & 15) * 64;
        const int lr = tid >> 4;
        const int lc = (tid & 15) * 4;
#pragma unroll
        for (int rr = 0; rr < 4; rr++) {
            const int row = lr + rr * 16;
            const float4 v = *(const float4*)(in + (size_t)(r0 + row) * DD + c0 + lc);
            tile[row][lc] = v.x; tile[row][lc + 1] = v.y;
            tile[row][lc + 2] = v.z; tile[row][lc + 3] = v.w;
        }
        __syncthreads();
#pragma unroll
        for (int rr = 0; rr < 4; rr++) {
            const int row = lr + rr * 16;
            bf16x4 o;
            o[0] = (__bf16)tile[lc + 0][row];
            o[1] = (__bf16)tile[lc + 1][row];
            o[2] = (__bf16)tile[lc + 2][row];
            o[3] = (__bf16)tile[lc + 3][row];
            *(bf16x4*)(out + (size_t)(c0 + row) * DD + r0 + lc) = o;
        }
        return;
    }
    // prep_vec
    const int pv = bid - 19200;
    const int lane = tid & 63, wave = tid >> 6;
    const int n = pv * 4 + wave;
    const float* row = k1w + (size_t)n * DD + lane * 16;
    float su = 0.f, sb = 0.f;
#pragma unroll
    for (int q = 0; q < 4; q++) {
        const float4 a = *(const float4*)(row + q * 4);
        const float4 g4 = *(const float4*)(lng + lane * 16 + q * 4);
        const float4 b4 = *(const float4*)(lnb + lane * 16 + q * 4);
        su += a.x * g4.x + a.y * g4.y + a.z * g4.z + a.w * g4.w;
        sb += a.x * b4.x + a.y * b4.y + a.z * b4.z + a.w * b4.w;
    }
#pragma unroll
    for (int off = 32; off > 0; off >>= 1) {
        su += __shfl_xor(su, off);
        sb += __shfl_xor(sb, off);
    }
    if (lane == 0) {
        u1[n] = su;
        c1b[n] = sb + k1b[n];
    }
}

// ---------------- paired tiny 1024^3 GEMMs: z=0 -> Gt, z=1 -> W2 ----------------
__global__ __launch_bounds__(256) void gemm_pair(const bf16* __restrict__ A0,
                                                 const bf16* __restrict__ W0,
                                                 bf16* __restrict__ O0,
                                                 const bf16* __restrict__ A1,
                                                 const bf16* __restrict__ W1,
                                                 bf16* __restrict__ O1) {
    const bf16* A = blockIdx.z ? A1 : A0;
    const bf16* W = blockIdx.z ? W1 : W0;
    bf16* O = blockIdx.z ? O1 : O0;
    __shared__ bf16 As[128 * BK];
    __shared__ bf16 Bs[128 * BK];
    const int tid = threadIdx.x;
    const int lane = tid & 63;
    const int wave = tid >> 6;
    const int wm = wave & 1;
    const int wn = wave >> 1;
    const int m0 = blockIdx.y * 128;
    const int n0 = blockIdx.x * 128;

    const int c = wave * 64 + lane;
    const int ar = c >> 2;
    const int ac = (c & 3) << 3;
    char* AsB = (char*)As;
    char* BsB = (char*)Bs;
    const int lr = lane & 15;
    const int lk = (lane >> 4) << 3;

    f32x4 acc[4][4] = {};

    for (int kt = 0; kt < DD; kt += BK) {
        const bf16* ga0 = A + (size_t)(m0 + ar) * DD + kt + ac;
        const bf16* gb0 = W + (size_t)(n0 + ar) * DD + kt + ac;
        GLOAD_LDS16(ga0, AsB + wave * 1024);
        GLOAD_LDS16(ga0 + (size_t)64 * DD, AsB + 4096 + wave * 1024);
        GLOAD_LDS16(gb0, BsB + wave * 1024);
        GLOAD_LDS16(gb0 + (size_t)64 * DD, BsB + 4096 + wave * 1024);
        __syncthreads();

        bf16x8 af[4], bfr[4];
#pragma unroll
        for (int i = 0; i < 4; i++)
            af[i] = *(const bf16x8*)&As[(wm * 64 + i * 16 + lr) * BK + lk];
#pragma unroll
        for (int j = 0; j < 4; j++)
            bfr[j] = *(const bf16x8*)&Bs[(wn * 64 + j * 16 + lr) * BK + lk];
#pragma unroll
        for (int i = 0; i < 4; i++)
#pragma unroll
            for (int j = 0; j < 4; j++)
                acc[i][j] = __builtin_amdgcn_mfma_f32_16x16x32_bf16(af[i], bfr[j], acc[i][j], 0, 0, 0);
        __syncthreads();
    }

#pragma unroll
    for (int i = 0; i < 4; i++) {
        const int row = m0 + wm * 64 + i * 16 + ((lane >> 4) << 2);
#pragma unroll
        for (int j = 0; j < 4; j++) {
            const int col = n0 + wn * 64 + j * 16 + (lane & 15);
#pragma unroll
            for (int rr = 0; rr < 4; rr++)
                O[(size_t)(row + rr) * DD + col] = (__bf16)acc[i][j][rr];
        }
    }
}

// ================ 256x256 K-loop, measured-best structure (R0: 70.6us) ==================
// K=1024, BK=64, 512 thr, 8 waves (2M x 4N). LDS 128 KiB = 2 buffers x (A 2-khalf + B
// 2-khalf slices of [256][32]). 2 barriers + 2 counted vmcnt(8) per K-tile; 32-MFMA
// clusters; swizzle (verified 0 bank conflicts): phys 16B slot = logical ^ ((row>>1)&3),
// via pre-swizzled GLOBAL source + swizzled ds_read address.

#define KL_STAGE_A(tt, hh, bb)                                               \
    {                                                                        \
        const bf16* gp_ = Aop + gofsA + (tt) * 64 + (hh) * 32;               \
        GLOAD_LDS16(gp_, smem + (bb) + (hh) * 16384 + ldsW);                 \
        GLOAD_LDS16(gp_ + (size_t)128 * DD,                                  \
                    smem + (bb) + (hh) * 16384 + 8192 + ldsW);               \
    }
#define KL_STAGE_B(tt, hh, bb)                                               \
    {                                                                        \
        const bf16* gp_ = Bop + gofsB + (tt) * 64 + (hh) * 32;               \
        GLOAD_LDS16(gp_, smem + (bb) + 32768 + (hh) * 16384 + ldsW);         \
        GLOAD_LDS16(gp_ + (size_t)128 * DD,                                  \
                    smem + (bb) + 32768 + (hh) * 16384 + 8192 + ldsW);       \
    }
#define KL_READS_A(ks, mh)                                                   \
    af[0] = *(const bf16x8*)(sA + bufo + (ks) * 16384 + (mh) * 4096);        \
    af[1] = *(const bf16x8*)(sA + bufo + (ks) * 16384 + (mh) * 4096 + 1024); \
    af[2] = *(const bf16x8*)(sA + bufo + (ks) * 16384 + (mh) * 4096 + 2048); \
    af[3] = *(const bf16x8*)(sA + bufo + (ks) * 16384 + (mh) * 4096 + 3072);
#define KL_READS_B(ks)                                                       \
    bfr[0] = *(const bf16x8*)(sB + bufo + (ks) * 16384);                     \
    bfr[1] = *(const bf16x8*)(sB + bufo + (ks) * 16384 + 1024);              \
    bfr[2] = *(const bf16x8*)(sB + bufo + (ks) * 16384 + 2048);              \
    bfr[3] = *(const bf16x8*)(sB + bufo + (ks) * 16384 + 3072);
#define KL_MFMA4(I, MH)                                                      \
    acc[(MH) * 4 + I][0] = __builtin_amdgcn_mfma_f32_16x16x32_bf16(af[I], bfr[0], acc[(MH) * 4 + I][0], 0, 0, 0); \
    acc[(MH) * 4 + I][1] = __builtin_amdgcn_mfma_f32_16x16x32_bf16(af[I], bfr[1], acc[(MH) * 4 + I][1], 0, 0, 0); \
    acc[(MH) * 4 + I][2] = __builtin_amdgcn_mfma_f32_16x16x32_bf16(af[I], bfr[2], acc[(MH) * 4 + I][2], 0, 0, 0); \
    acc[(MH) * 4 + I][3] = __builtin_amdgcn_mfma_f32_16x16x32_bf16(af[I], bfr[3], acc[(MH) * 4 + I][3], 0, 0, 0);
#define KL_MFMA16(MH)                                                        \
    __builtin_amdgcn_s_setprio(1);                                           \
    KL_MFMA4(0, MH) KL_MFMA4(1, MH) KL_MFMA4(2, MH) KL_MFMA4(3, MH)          \
    __builtin_amdgcn_s_setprio(0);
#define KL_BARRIER(N) asm volatile("s_waitcnt vmcnt(" #N ")\n\ts_barrier" ::: "memory")

__device__ __forceinline__ void kloop256(const bf16* __restrict__ Aop,
                                         const bf16* __restrict__ Bop,
                                         const int m0, const int n0,
                                         char* smem, f32x4 (&acc)[8][4],
                                         const int tid, const int lane,
                                         const int wave, const int wm, const int wn) {
    // stage addressing: thread t -> slice row (t>>2)+q*128, 16B slot (t&3)^((t>>3)&3)
    const int grow = tid >> 2;
    const int gslot = (tid & 3) ^ ((tid >> 3) & 3);
    const size_t gofsA = (size_t)(m0 + grow) * DD + gslot * 8;
    const size_t gofsB = (size_t)(n0 + grow) * DD + gslot * 8;
    const int ldsW = wave * 1024;  // HW adds lane*16
    // read addressing: row = <base16> + (lane&15), slot = (lane>>4) ^ ((lane>>1)&3)
    const int sxo = (((lane >> 4) ^ ((lane >> 1) & 3)) << 4);
    const char* sA = smem + wm * 8192 + (lane & 15) * 64 + sxo;
    const char* sB = smem + 32768 + wn * 4096 + (lane & 15) * 64 + sxo;

    bf16x8 af[4], bfr[4];

    // prologue: 6 slices, 12 loads
    KL_STAGE_A(0, 0, 0) KL_STAGE_B(0, 0, 0)
    KL_STAGE_A(0, 1, 0) KL_STAGE_B(0, 1, 0)
    KL_STAGE_A(1, 0, 65536) KL_STAGE_B(1, 0, 65536)

    int bufo = 0;
    for (int t = 0; t < 15; t++) {
        const int nb = bufo ^ 65536;
        KL_BARRIER(8);                   // A[t][0],B[t][0] landed; 4 slices in flight
        KL_READS_A(0, 0) KL_READS_B(0)
        KL_STAGE_A(t + 1, 1, nb)
        KL_MFMA16(0)
        KL_READS_A(0, 1)
        KL_STAGE_B(t + 1, 1, nb)
        KL_MFMA16(1)
        KL_BARRIER(8);                   // A[t][1],B[t][1] landed
        KL_READS_A(1, 0) KL_READS_B(1)
        if (t < 14) { KL_STAGE_A(t + 2, 0, bufo) }
        KL_MFMA16(0)
        KL_READS_A(1, 1)
        if (t < 14) { KL_STAGE_B(t + 2, 0, bufo) }
        KL_MFMA16(1)
        bufo = nb;
    }
    // peeled t = 15 (bufo == 65536)
    KL_BARRIER(4);
    KL_READS_A(0, 0) KL_READS_B(0)
    KL_MFMA16(0)
    KL_READS_A(0, 1)
    KL_MFMA16(1)
    KL_BARRIER(0);
    KL_READS_A(1, 0) KL_READS_B(1)
    KL_MFMA16(0)
    KL_READS_A(1, 1)
    KL_MFMA16(1)
}

// ---------------- merged U / Vt2 GEMM: 256x256 tiles, 512 threads, grid 512 ----------
__global__ __launch_bounds__(512) void gemm_uv(const bf16* __restrict__ xb,
                                               const bf16* __restrict__ Gt,
                                               const bf16* __restrict__ W2,
                                               bf16* __restrict__ Ub,
                                               bf16* __restrict__ Vt2) {
    __shared__ char smem[131072];
    const int s = blockIdx.x;
    const int half = s >> 8;
    const int sh = s & 255;
    const int p = (sh & 7) | ((sh >> 5) << 3);  // xb panel 0..63; p % 8 == s % 8
    const int q = (sh >> 3) & 3;
    const bf16* A;
    const bf16* W;
    bf16* O;
    int m0, n0;
    size_t ldo;
    if (half == 0) {
        A = xb; W = Gt; O = Ub;
        m0 = p * 256; n0 = q * 256; ldo = DD;
    } else {
        A = W2; W = xb; O = Vt2;
        m0 = q * 256; n0 = p * 256; ldo = (size_t)4 * SS;
    }
    const int tid = threadIdx.x;
    const int lane = tid & 63;
    const int wave = tid >> 6;
    const int wm = wave & 1;
    const int wn = wave >> 1;

    f32x4 acc[8][4] = {};
    kloop256(A, W, m0, n0, smem, acc, tid, lane, wave, wm, wn);

#pragma unroll
    for (int a = 0; a < 8; a++) {
        const int row = m0 + wm * 128 + a * 16 + ((lane >> 4) << 2);
#pragma unroll
        for (int j = 0; j < 4; j++) {
            const int col = n0 + wn * 64 + j * 16 + (lane & 15);
#pragma unroll
            for (int rr = 0; rr < 4; rr++)
                O[(size_t)(row + rr) * ldo + col] = (__bf16)acc[a][j][rr];
        }
    }
}

// ---------------- k1 GEMM (256x256), folded LN1, partial-only output ------
__global__ __launch_bounds__(512) void gemm_k1(const bf16* __restrict__ T,
                                               const bf16* __restrict__ k1g,
                                               const float* __restrict__ part_t,
                                               const float* __restrict__ u1,
                                               const float* __restrict__ c1b,
                                               const float* __restrict__ lng,
                                               const float* __restrict__ k2w,
                                               float* __restrict__ part_h) {
    __shared__ char smem[131072];
    __shared__ float lmu[256], lrs[256];
    const int m0 = blockIdx.x * 256;
    const int n0 = blockIdx.y * 256;
    const int tid = threadIdx.x;
    const int lane = tid & 63;
    const int wave = tid >> 6;
    const int wm = wave & 1;
    const int wn = wave >> 1;

    // per-row LN1 stats from part_t (exact)
    if (tid < 256) {
        const float* p = part_t + (size_t)(m0 + tid) * 32;
        float s1 = 0.f, s2 = 0.f;
#pragma unroll
        for (int s = 0; s < 8; s++) {
            const float4 v = *(const float4*)(p + s * 4);
            s1 += v.x + v.z;
            s2 += v.y + v.w;
        }
        const float m = s1 * (1.f / DD);
        lmu[tid] = m;
        lrs[tid] = rsqrtf(s2 * (1.f / DD) - m * m + LN_EPS);
    }
    __syncthreads();  // publishes lmu/lrs; drains part_t loads so vmcnt counting starts at 0

    f32x4 acc[8][4] = {};
    kloop256(T, k1g, m0, n0, smem, acc, tid, lane, wave, wm, wn);

    float u1v[4], cbv[4], ugv[4];
#pragma unroll
    for (int j = 0; j < 4; j++) {
        const int col = n0 + wn * 64 + j * 16 + (lane & 15);
        u1v[j] = u1[col];
        cbv[j] = c1b[col];
        ugv[j] = lng[col] * k2w[col];
    }
    const int strip = blockIdx.y * 4 + wn;  // 16 strips of 64 cols
#pragma unroll
    for (int a = 0; a < 8; a++) {
#pragma unroll
        for (int rr = 0; rr < 4; rr++) {
            const int lrow = wm * 128 + a * 16 + ((lane >> 4) << 2) + rr;
            const int row = m0 + lrow;
            const float mr = lmu[lrow], rs = lrs[lrow];
            float s1 = 0.f, s2 = 0.f, s3 = 0.f;
#pragma unroll
            for (int j = 0; j < 4; j++) {
                const float v = rs * (acc[a][j][rr] - mr * u1v[j]) + cbv[j];
                const float h = fmaxf(v, 0.f);
                s1 += h; s2 += h * h; s3 += h * ugv[j];
            }
#pragma unroll
            for (int off = 8; off > 0; off >>= 1) {
                s1 += __shfl_xor(s1, off);
                s2 += __shfl_xor(s2, off);
                s3 += __shfl_xor(s3, off);
            }
            if ((lane & 15) == 0) {
                float* p = part_h + (size_t)row * 48 + strip * 3;
                p[0] = s1; p[1] = s2; p[2] = s3;
            }
        }
    }
}

// ---------------- FUSED attention A v2: S = U @ x_band^T -> masked softmax -> bf16 P ----
// 64x384 tile, 512 thr (8 waves 2M x 4N), K=1024, BK=64 DOUBLE-BUFFERED (kloop structure):
// per K-tile {vmcnt(7)+barrier -> 16 ds_read frags -> 12 MFMA kh0 -> lgkm(0)+barrier ->
// stage next-next tile (7 gload/thread) -> 12 MFMA kh1}. Counted vmcnt, never 0 mid-loop.
// LDS/buffer: A[2kh][64][32] @0 (8K), B[2kh][384][32] @8192 (48K) = 56K; x2 = 112K.
// Ledger: BARRIER(7) at iter t leaves tile t+1's 7 loads in flight -> tile t confirmed;
// stage of t+2 into buf(t&1) follows the lgkm-barrier after all waves' reads of tile t.
// Same XOR swizzle as kloop256 (pre-swizzled global src + swizzled ds_read). Band reads
// OOB land in Ub/Vt2 guard regions (valid bf16), masked in softmax.
#define SP_STAGE(tt, bb)                                                      \
    {                                                                         \
        const int kt_ = (tt) * 64;                                            \
        GLOAD_LDS16(U + gofsA + kt_, smem + (bb) + ldsWA);                    \
        GLOAD_LDS16(X + gofsB + kt_, smem + (bb) + 8192 + ldsW);              \
        GLOAD_LDS16(X + gofsB + (long)128 * DD + kt_, smem + (bb) + 16384 + ldsW); \
        GLOAD_LDS16(X + gofsB + (long)256 * DD + kt_, smem + (bb) + 24576 + ldsW); \
        GLOAD_LDS16(X + gofsB + kt_ + 32, smem + (bb) + 32768 + ldsW);        \
        GLOAD_LDS16(X + gofsB + (long)128 * DD + kt_ + 32, smem + (bb) + 40960 + ldsW); \
        GLOAD_LDS16(X + gofsB + (long)256 * DD + kt_ + 32, smem + (bb) + 49152 + ldsW); \
    }
#define SP_READS(bb)                                                          \
    _Pragma("unroll") for (int i_ = 0; i_ < 2; i_++) {                        \
        a0[i_] = *(const bf16x8*)(sA + (bb) + wm * 2048 + i_ * 1024);         \
        a1[i_] = *(const bf16x8*)(sA + (bb) + 4096 + wm * 2048 + i_ * 1024);  \
    }                                                                         \
    _Pragma("unroll") for (int j_ = 0; j_ < 6; j_++) {                        \
        b0[j_] = *(const bf16x8*)(sB + (bb) + wn * 6144 + j_ * 1024);         \
        b1[j_] = *(const bf16x8*)(sB + (bb) + 24576 + wn * 6144 + j_ * 1024); \
    }
#define SP_MFMA(AR, BR)                                                       \
    __builtin_amdgcn_s_setprio(1);                                            \
    _Pragma("unroll") for (int i_ = 0; i_ < 2; i_++)                          \
        _Pragma("unroll") for (int j_ = 0; j_ < 6; j_++)                      \
            acc[i_][j_] = __builtin_amdgcn_mfma_f32_16x16x32_bf16(AR[i_], BR[j_], acc[i_][j_], 0, 0, 0); \
    __builtin_amdgcn_s_setprio(0);
#define SP_LGBAR asm volatile("s_waitcnt lgkmcnt(0)\n\ts_barrier" ::: "memory")

__global__ __launch_bounds__(512) void attn_sp(const bf16* __restrict__ U,
                                               const bf16* __restrict__ X,
                                               bf16* __restrict__ P) {
    __shared__ char smem[114688];
    const int s = blockIdx.x;
    const int t = (s & 7) * 32 + (s >> 3);  // XCD-contiguous t chunks
    const int tid = threadIdx.x;
    const int lane = tid & 63;
    const int wave = tid >> 6;
    const int wm = wave & 1;       // 2 row-groups of 32
    const int wn = wave >> 1;      // 4 col-groups of 96
    const int m0 = t * 64;
    const long w0 = (long)(t >> 1) * 128 - 128;  // band start; OOB -> guard buffers

    const int grow = tid >> 2;
    const int gslot = (tid & 3) ^ ((tid >> 3) & 3);
    // A: waves 0-3 stage kh0, waves 4-7 stage kh1 (rows 0..63 each, col +kh*32)
    const size_t gofsA = (size_t)(m0 + (grow & 63)) * DD + gslot * 8 + (wave >> 2) * 32;
    const long gofsB = (w0 + grow) * (long)DD + gslot * 8;
    const int ldsWA = (wave & 3) * 1024 + (wave >> 2) * 4096;
    const int ldsW = wave * 1024;  // HW adds lane*16
    const int sxo = (((lane >> 4) ^ ((lane >> 1) & 3)) << 4);
    const char* sA = smem + (lane & 15) * 64 + sxo;
    const char* sB = smem + 8192 + (lane & 15) * 64 + sxo;

    f32x4 acc[2][6] = {};
    bf16x8 a0[2], b0[6], a1[2], b1[6];

    SP_STAGE(0, 0)
    SP_STAGE(1, 57344)

#pragma unroll 1
    for (int tt = 0; tt < 14; tt++) {
        const int bb = (tt & 1) * 57344;
        KL_BARRIER(7);            // tile tt confirmed; tile tt+1's 7 in flight
        SP_READS(bb)
        SP_MFMA(a0, b0)
        SP_LGBAR;                 // all waves' reads of buf bb complete
        SP_STAGE(tt + 2, bb)
        SP_MFMA(a1, b1)
    }
    // peeled tt = 14 (bb = 0): confirm T14 (drain 14 -> 7), no stage
    KL_BARRIER(7);
    SP_READS(0)
    SP_MFMA(a0, b0)
    SP_MFMA(a1, b1)
    // peeled tt = 15 (bb = 57344): drain all
    KL_BARRIER(0);
    SP_READS(57344)
    SP_MFMA(a0, b0)
    SP_MFMA(a1, b1)
    __syncthreads();

    // ---- masked softmax over the 384-wide band, rows = m0 .. m0+63 ----
    float* lredm = (float*)smem;      // [64 rows][4 wn]  (overlays buf0 A region)
    float* lreds = lredm + 256;       // [64 rows][4 wn]
    const int rbase = wm * 32 + ((lane >> 4) << 2);     // + i*16 + rr
    const int ib = (t << 6) & (SS - 1);                 // in-batch row base
    const int jst = ((t >> 1) & 31) * 128 - 128;        // in-batch band start
    const float scale = 0.03125f;

    float pmx[2][4];
#pragma unroll
    for (int i = 0; i < 2; i++)
#pragma unroll
        for (int rr = 0; rr < 4; rr++) {
            const int irow = ib + rbase + i * 16 + rr;
            float mx = -INFINITY;
#pragma unroll
            for (int j = 0; j < 6; j++) {
                const int jg = jst + wn * 96 + j * 16 + (lane & 15);
                const int dj = jg - irow;
                const bool valid = (jg >= 0) && (jg < SS) && (dj != 0) && (dj <= AP) && (dj >= -AP);
                const float sv = valid ? acc[i][j][rr] * scale : -INFINITY;
                acc[i][j][rr] = sv;
                mx = fmaxf(mx, sv);
            }
#pragma unroll
            for (int off = 8; off > 0; off >>= 1) mx = fmaxf(mx, __shfl_xor(mx, off));
            pmx[i][rr] = mx;
        }
    if ((lane & 15) == 0) {
#pragma unroll
        for (int i = 0; i < 2; i++)
#pragma unroll
            for (int rr = 0; rr < 4; rr++)
                lredm[(rbase + i * 16 + rr) * 4 + wn] = pmx[i][rr];
    }
    __syncthreads();

    float lsum[2][4], mv[2][4];
#pragma unroll
    for (int i = 0; i < 2; i++)
#pragma unroll
        for (int rr = 0; rr < 4; rr++) {
            const int ri = (rbase + i * 16 + rr) * 4;
            mv[i][rr] = fmaxf(fmaxf(lredm[ri], lredm[ri + 1]),
                              fmaxf(lredm[ri + 2], lredm[ri + 3]));
            float su = 0.f;
#pragma unroll
            for (int j = 0; j < 6; j++) {
                const float e = __expf(acc[i][j][rr] - mv[i][rr]);
                acc[i][j][rr] = e;
                su += e;
            }
#pragma unroll
            for (int off = 8; off > 0; off >>= 1) su += __shfl_xor(su, off);
            lsum[i][rr] = su;
        }
    if ((lane & 15) == 0) {
#pragma unroll
        for (int i = 0; i < 2; i++)
#pragma unroll
            for (int rr = 0; rr < 4; rr++)
                lreds[(rbase + i * 16 + rr) * 4 + wn] = lsum[i][rr];
    }
    __syncthreads();

#pragma unroll
    for (int i = 0; i < 2; i++)
#pragma unroll
        for (int rr = 0; rr < 4; rr++) {
            const int ri = (rbase + i * 16 + rr) * 4;
            const float inv = 1.f / (lreds[ri] + lreds[ri + 1] + lreds[ri + 2] + lreds[ri + 3]);
            const size_t ro = (size_t)(m0 + rbase + i * 16 + rr) * BAND;
#pragma unroll
            for (int j = 0; j < 6; j++)
                P[ro + wn * 96 + j * 16 + (lane & 15)] = (__bf16)(acc[i][j][rr] * inv);
        }
}

// ---------------- attention pass B + residual + T row-partials ----------------
// 128x256 tiles, 512 threads, grid (x = 128 t, y = 4 n-blocks of 256)
__global__ __launch_bounds__(512) void attn_pv_mfma(const bf16* __restrict__ P,
                                                    const bf16* __restrict__ Vt,
                                                    const bf16* __restrict__ xres,
                                                    bf16* __restrict__ T,
                                                    float* __restrict__ part_t) {
    __shared__ bf16 As[128 * BK];   // P tile   8KB
    __shared__ bf16 Bs[256 * BK];   // Vt tile 16KB
    const int tid = threadIdx.x;
    const int lane = tid & 63;
    const int wave = tid >> 6;     // 0..7
    const int wm = wave & 1;       // 2 m-strips of 64
    const int wn = wave >> 1;      // 4 n-strips of 64
    const int t = blockIdx.x;
    const int m0 = t * 128;
    const int n0 = blockIdx.y * 256;
    const bf16* Wb = Vt + (long)t * 128 - 128;

    const int ar = tid >> 2;           // 0..127
    const int ac = (tid & 3) << 3;
    char* AsB = (char*)As;
    char* BsB = (char*)Bs;
    const int lr = lane & 15;
    const int lk = (lane >> 4) << 3;

    f32x4 acc[4][4] = {};

    for (int kt = 0; kt < BAND; kt += BK) {
        const bf16* ga0 = P + (size_t)(m0 + ar) * BAND + kt + ac;
        const bf16* gb0 = Wb + (size_t)(n0 + ar) * (4 * SS) + kt + ac;
        GLOAD_LDS16(ga0, AsB + wave * 1024);
        GLOAD_LDS16(gb0, BsB + wave * 1024);
        GLOAD_LDS16(gb0 + (size_t)128 * (4 * SS), BsB + 8192 + wave * 1024);
        __syncthreads();

        bf16x8 af[4], bfr[4];
#pragma unroll
        for (int i = 0; i < 4; i++)
            af[i] = *(const bf16x8*)&As[(wm * 64 + i * 16 + lr) * BK + lk];
#pragma unroll
        for (int j = 0; j < 4; j++)
            bfr[j] = *(const bf16x8*)&Bs[(wn * 64 + j * 16 + lr) * BK + lk];
#pragma unroll
        for (int i = 0; i < 4; i++)
#pragma unroll
            for (int j = 0; j < 4; j++)
                acc[i][j] = __builtin_amdgcn_mfma_f32_16x16x32_bf16(af[i], bfr[j], acc[i][j], 0, 0, 0);
        __syncthreads();
    }

    const int strip = blockIdx.y * 4 + wn;  // 16 strips of 64 cols
#pragma unroll
    for (int i = 0; i < 4; i++) {
#pragma unroll
        for (int rr = 0; rr < 4; rr++) {
            const int row = m0 + wm * 64 + i * 16 + ((lane >> 4) << 2) + rr;
            float s1 = 0.f, s2 = 0.f;
#pragma unroll
            for (int j = 0; j < 4; j++) {
                const int col = n0 + wn * 64 + j * 16 + (lane & 15);
                const size_t idx = (size_t)row * DD + col;
                const __bf16 tv_b = (__bf16)(acc[i][j][rr] + (float)xres[idx]);
                T[idx] = tv_b;
                const float tv = (float)tv_b;
                s1 += tv; s2 += tv * tv;
            }
#pragma unroll
            for (int off = 8; off > 0; off >>= 1) {
                s1 += __shfl_xor(s1, off);
                s2 += __shfl_xor(s2, off);
            }
            if ((lane & 15) == 0) {
                float2 st; st.x = s1; st.y = s2;
                *(float2*)(part_t + (size_t)row * 32 + strip * 2) = st;
            }
        }
    }
}

// ---------------- reduce H partials -> sigmoid head ----------------
__global__ __launch_bounds__(256) void ln_k2_p(const float* __restrict__ part_h,
                                               const float* __restrict__ g,
                                               const float* __restrict__ bta,
                                               const float* __restrict__ w2,
                                               const float* __restrict__ b2,
                                               float* __restrict__ out) {
    __shared__ float red[256], red2[256];
    const int tid = threadIdx.x;
    const float4 g4 = *(const float4*)(g + tid * 4);
    const float4 w4 = *(const float4*)(w2 + tid * 4);
    const float4 b4 = *(const float4*)(bta + tid * 4);
    red[tid] = g4.x * w4.x + g4.y * w4.y + g4.z * w4.z + g4.w * w4.w;
    red2[tid] = b4.x * w4.x + b4.y * w4.y + b4.z * w4.z + b4.w * w4.w;
    __syncthreads();
    for (int s = 128; s > 0; s >>= 1) {
        if (tid < s) { red[tid] += red[tid + s]; red2[tid] += red2[tid + s]; }
        __syncthreads();
    }
    const float sum_u = red[0];
    const float sum_bw = red2[0];

    const int r = blockIdx.x * 256 + tid;
    const float* p = part_h + (size_t)r * 48;
    float s1 = 0.f, s2 = 0.f, s3 = 0.f;
#pragma unroll
    for (int s = 0; s < 16; s++) {
        s1 += p[s * 3 + 0];
        s2 += p[s * 3 + 1];
        s3 += p[s * 3 + 2];
    }
    const float m = s1 * (1.f / DD);
    const float var = s2 * (1.f / DD) - m * m;
    const float rs = rsqrtf(var + LN_EPS);
    const float z = rs * (s3 - m * sum_u) + sum_bw + b2[0];
    out[r] = 1.f / (1.f + __expf(-z));
}

extern "C" void kernel_launch(void* const* d_in, const int* in_sizes, int n_in,
                              void* d_out, int out_size, void* d_ws, size_t ws_size,
                              hipStream_t stream) {
    const float* x   = (const float*)d_in[0];
    const float* Wq  = (const float*)d_in[1];
    const float* Wk  = (const float*)d_in[2];
    const float* Wv  = (const float*)d_in[3];
    const float* Wo  = (const float*)d_in[4];
    const float* k1w = (const float*)d_in[5];
    const float* k1b = (const float*)d_in[6];
    const float* k2w = (const float*)d_in[7];
    const float* k2b = (const float*)d_in[8];
    const float* lng = (const float*)d_in[9];
    const float* lnb = (const float*)d_in[10];
    float* out = (float*)d_out;

    const int N = 4 * SS;  // 16384 rows
    char* ws = (char*)d_ws;
    // layout (MB). Banded passes read +/-512KB around xb and +/-256KB around Vt2 ->
    // neighbors must be valid bf16 (Ub | xb | Vt2 | P). Masked / zero-weighted.
    bf16*  Ub   = (bf16*)(ws);                          //   0..32
    bf16*  xb   = (bf16*)(ws + ((size_t)32  << 20));    //  32..64
    bf16*  Vt2  = (bf16*)(ws + ((size_t)64  << 20));    //  64..96  [1024][16384]
    bf16*  P    = (bf16*)(ws + ((size_t)96  << 20));    //  96..108
    bf16*  T    = (bf16*)(ws + ((size_t)164 << 20));    // 164..196
    bf16*  Wtb  = (bf16*)(ws + ((size_t)196 << 20));    // 196..202: Wq^T, Wk^T, Wv^T
    bf16*  Wqtb = Wtb;
    bf16*  Wktb = Wqtb + (1 << 20);
    bf16*  Wvtb = Wktb + (1 << 20);
    bf16*  Wob  = Wvtb + (1 << 20);                     // 202..204
    bf16*  k1g  = Wob  + (1 << 20);                     // 204..206
    bf16*  Gtb  = k1g  + (1 << 20);                     // 206..208
    bf16*  W2b  = Gtb  + (1 << 20);                     // 208..210
    float* u1     = (float*)(ws + ((size_t)210 << 20)); // 4 KB
    float* c1b    = u1 + DD;                            // 4 KB
    float* part_t = (float*)(ws + ((size_t)211 << 20)); // 211..213: [16384][16][2]
    float* part_h = (float*)(ws + ((size_t)214 << 20)); // 214..217: [16384][16][3]

    dim3 tb(256);

    prep_all<<<19456, tb, 0, stream>>>(x, Wq, Wk, Wv, Wo, k1w, k1b, lng, lnb,
                                       xb, Wob, k1g, Wtb, u1, c1b);

    // Gt = Wk^T @ Wq (bt-layout)  |  W2 = Wo @ Wv (bt on Wv^T)
    gemm_pair<<<dim3(8, 8, 2), tb, 0, stream>>>(Wktb, Wqtb, Gtb, Wob, Wvtb, W2b);

    gemm_uv<<<512, dim3(512), 0, stream>>>(xb, Gtb, W2b, Ub, Vt2);

    attn_sp<<<256, dim3(512), 0, stream>>>(Ub, xb, P);
    attn_pv_mfma<<<dim3(N / 128, 4), dim3(512), 0, stream>>>(P, Vt2, xb, T, part_t);

    gemm_k1<<<dim3(64, 4), dim3(512), 0, stream>>>(T, k1g, part_t, u1, c1b, lng, k2w, part_h);
    ln_k2_p<<<N / 256, tb, 0, stream>>>(part_h, lng, lnb, k2w, k2b, out);
}